// Round 1
// baseline (116.864 us; speedup 1.0000x reference)
//
#include <hip/hip_runtime.h>

#define NH 6
#define HEAD_DIM 32
#define CCH 192
#define HH 56
#define WW 56
#define HWSZ (HH * WW)            // 3136
#define KPOS 9
#define SCALE 0.17677669529663687f  // 32^-0.5
#define XPAD 61                   // x-stride: conflict-free reads & writes (R5-proven; still 2-way max with 8c x 4d lane split)
#define ROWSZ (HEAD_DIM * XPAD)   // 1952 floats per staged row-plane
#define JROWS 4                   // output rows per block (same parity)
#define STRIPS 7                  // strips per parity (7*4 = 28 rows)
#define NT 512                    // 8 waves/block: same 46.8KB LDS ring now feeds 2x the waves
#define SELEMS (HEAD_DIM * WW)    // 1792 staged elems per row-plane

// Block = (bh, parity, strip). Outputs rows y0+2j, j=0..3. LDS = 3-slot ring
// of k/v row-planes in [d][x'] layout (XPAD 61, zero-pad baked in).
// vs the 256-thread version: each pixel is owned by 8 lanes (c=0..7) x 4 dims,
// so 672 blocks x 8 waves = 24 waves/CU (was 12) at identical LDS/HBM cost.
// Rolling schedule unchanged: prefetch row r=j+3 (and next q) into regs DURING
// compute of row j, commit to slot j%3 after the barrier.
__global__ __launch_bounds__(NT, 6) void dilate_attn_roll8(
    const float* __restrict__ q,
    const float* __restrict__ k,
    const float* __restrict__ v,
    float* __restrict__ out)
{
    __shared__ float ks[3][ROWSZ];
    __shared__ float vs[3][ROWSZ];

    // bh fastest -> (bh, strip±1) partners 48 apart (same XCD, co-resident)
    const int bh     = blockIdx.x % 48;
    const int ps     = blockIdx.x / 48;
    const int parity = ps / STRIPS;
    const int s      = ps % STRIPS;
    const int y0     = parity + 8 * s;    // output rows y0 + 2j
    const int t      = threadIdx.x;

    const size_t plane = (size_t)bh * HEAD_DIM * HWSZ;
    const int px = t >> 3;                // 0..63 (valid < 56)
    const int c  = t & 7;                 // dim-quad index (4 dims per lane)
    const bool active = px < WW;

    // staging element map: 4 elems/thread, last one guarded (1792 = 3.5*512)
    int sd[4], sx[4];
    bool sv[4];
#pragma unroll
    for (int i = 0; i < 4; i++) {
        const int e = t + NT * i;
        sv[i] = (e < SELEMS);
        const int ee = sv[i] ? e : 0;
        sd[i] = ee / WW;
        sx[i] = ee - sd[i] * WW;
    }

    // ---- q for row 0 (issue first; overlaps prologue staging) ----
    float qcur[4];
    if (active) {
        const float* qb = q + plane + (size_t)(4 * c) * HWSZ + (size_t)y0 * WW + px;
#pragma unroll
        for (int d = 0; d < 4; d++) qcur[d] = qb[d * HWSZ];
    }

    // ---- zero pad columns x' in {0,1,58,59} for all 3 slots (done ONCE;
    //      row data never overwrites pads) ----
    if (t < 3 * HEAD_DIM * 4) {
        const int slot = t >> 7;
        const int rr   = t & 127;
        const int d    = rr >> 2;
        const int xc   = rr & 3;
        const int xp   = (xc < 2) ? xc : (56 + xc);
        ks[slot][d * XPAD + xp] = 0.0f;
        vs[slot][d * XPAD + xp] = 0.0f;
    }

    // ---- prologue: stage rows r=0,1,2 (ky = y0-2+2r) into slots 0,1,2.
    //      Issue ALL loads first (max loads in flight), then all commits. ----
    float kp[3][4], vp[3][4];
#pragma unroll
    for (int r = 0; r < 3; r++) {
        const int ky   = y0 - 2 + 2 * r;
        const bool okr = ((unsigned)ky < HH);
        const float* kb = k + plane + (size_t)(okr ? ky : 0) * WW;
        const float* vb = v + plane + (size_t)(okr ? ky : 0) * WW;
#pragma unroll
        for (int i = 0; i < 4; i++) {
            const size_t g = (size_t)sd[i] * HWSZ + sx[i];
            const bool ok  = okr && sv[i];
            kp[r][i] = ok ? kb[g] : 0.0f;
            vp[r][i] = ok ? vb[g] : 0.0f;
        }
    }
#pragma unroll
    for (int r = 0; r < 3; r++) {
#pragma unroll
        for (int i = 0; i < 4; i++) {
            if (sv[i]) {
                const int a = sd[i] * XPAD + sx[i] + 2;
                ks[r][a] = kp[r][i];
                vs[r][a] = vp[r][i];
            }
        }
    }
    __syncthreads();

    // ---- main rolling loop over the 4 output rows ----
    float qnxt[4], kn[4], vn[4];
#pragma unroll
    for (int j = 0; j < JROWS; j++) {
        const int y = y0 + 2 * j;

        // prefetch staged row r=j+3 (ky = y0+4+2j) + next q into registers
        if (j < JROWS - 1) {
            const int ky   = y0 + 4 + 2 * j;       // always >= 4
            const bool okr = (ky < HH);
            const float* kb = k + plane + (size_t)(okr ? ky : 0) * WW;
            const float* vb = v + plane + (size_t)(okr ? ky : 0) * WW;
#pragma unroll
            for (int i = 0; i < 4; i++) {
                const size_t g = (size_t)sd[i] * HWSZ + sx[i];
                const bool ok  = okr && sv[i];
                kn[i] = ok ? kb[g] : 0.0f;
                vn[i] = ok ? vb[g] : 0.0f;
            }
            if (active) {
                const float* qb = q + plane + (size_t)(4 * c) * HWSZ + (size_t)(y + 2) * WW + px;
#pragma unroll
                for (int d = 0; d < 4; d++) qnxt[d] = qb[d * HWSZ];
            }
        }

        // compute output row j from slots (j+r')%3, r'=0..2 (loads in flight)
        if (active) {
            float lg[KPOS];
#pragma unroll
            for (int rp = 0; rp < 3; rp++) {
                const float* kr = &ks[(j + rp) % 3][(4 * c) * XPAD + px];
                float a0 = 0.f, a1 = 0.f, a2 = 0.f;
#pragma unroll
                for (int d = 0; d < 4; d++) {
                    const float* p  = kr + d * XPAD;
                    const float qd = qcur[d];
                    a0 = fmaf(qd, p[0], a0);
                    a1 = fmaf(qd, p[2], a1);
                    a2 = fmaf(qd, p[4], a2);
                }
                lg[3 * rp + 0] = a0;
                lg[3 * rp + 1] = a1;
                lg[3 * rp + 2] = a2;
            }
            // reduce partial dots across the 8 lanes owning this pixel
#pragma unroll
            for (int kk = 0; kk < KPOS; kk++) {
                float sm = lg[kk];
                sm += __shfl_xor(sm, 1);
                sm += __shfl_xor(sm, 2);
                sm += __shfl_xor(sm, 4);
                lg[kk] = sm * SCALE;
            }
            float m = lg[0];
#pragma unroll
            for (int kk = 1; kk < KPOS; kk++) m = fmaxf(m, lg[kk]);
            float ssum = 0.f;
#pragma unroll
            for (int kk = 0; kk < KPOS; kk++) {
                lg[kk] = __expf(lg[kk] - m);
                ssum += lg[kk];
            }
            const float inv = 1.f / ssum;

            float acc[4] = {0.f, 0.f, 0.f, 0.f};
#pragma unroll
            for (int rp = 0; rp < 3; rp++) {
                const float* vr = &vs[(j + rp) % 3][(4 * c) * XPAD + px];
                const float w0 = lg[3 * rp + 0] * inv;
                const float w1 = lg[3 * rp + 1] * inv;
                const float w2 = lg[3 * rp + 2] * inv;
#pragma unroll
                for (int d = 0; d < 4; d++) {
                    const float* p = vr + d * XPAD;
                    float a = acc[d];
                    a = fmaf(w0, p[0], a);
                    a = fmaf(w1, p[2], a);
                    a = fmaf(w2, p[4], a);
                    acc[d] = a;
                }
            }

            const int h = bh % NH;
            const int b = bh / NH;
            float* ob = out + ((size_t)((b * HH + y) * WW + px)) * CCH
                            + h * HEAD_DIM + 4 * c;
            *reinterpret_cast<float4*>(ob) = make_float4(acc[0], acc[1], acc[2], acc[3]);
        }

        if (j < JROWS - 1) {
            __syncthreads();    // all waves done reading slot j%3

            // commit prefetched row r=j+3 into slot j%3; roll q
#pragma unroll
            for (int i = 0; i < 4; i++) {
                if (sv[i]) {
                    const int a = sd[i] * XPAD + sx[i] + 2;
                    ks[j % 3][a] = kn[i];
                    vs[j % 3][a] = vn[i];
                }
            }
#pragma unroll
            for (int d = 0; d < 4; d++) qcur[d] = qnxt[d];

            __syncthreads();    // new slot contents visible before next compute
        }
    }
}

extern "C" void kernel_launch(void* const* d_in, const int* in_sizes, int n_in,
                              void* d_out, int out_size, void* d_ws, size_t ws_size,
                              hipStream_t stream) {
    const float* q = (const float*)d_in[0];
    const float* k = (const float*)d_in[1];
    const float* v = (const float*)d_in[2];
    float* out = (float*)d_out;

    const int blocks = 48 * 2 * STRIPS;   // 672 — fully co-resident at 3/CU, now 24 waves/CU
    dilate_attn_roll8<<<blocks, NT, 0, stream>>>(q, k, v, out);
}

// Round 2
// 104.797 us; speedup vs baseline: 1.1151x; 1.1151x over previous
//
#include <hip/hip_runtime.h>

#define NH 6
#define HEAD_DIM 32
#define CCH 192
#define HH 56
#define WW 56
#define HWSZ (HH * WW)            // 3136
#define KPOS 9
// 32^-0.5 * log2(e): fold softmax scale into exp2 domain
#define SCALE_LOG2E 0.25503486f
#define XPAD 61                   // x-stride: conflict-free reads & writes (R5-proven)
#define ROWSZ (HEAD_DIM * XPAD)   // 1952 floats per staged row-plane
#define JROWS 4                   // output rows per block (same parity)
#define STRIPS 7                  // strips per parity (7*4 = 28 rows)

// DPP quad_perm cross-lane adds: pure-VALU replacement for __shfl_xor(x,1/2),
// which lowers to ds_bpermute (LDS pipe — the saturated resource, per R1 A/B).
// Reduction is within quads of 4 lanes (c = lane&3, quad = pixel); quad_perm
// [1,0,3,2] = xor1, [2,3,0,1] = xor2. Guard (px<56) is quad-uniform, so DPP
// source lanes are always active inside the guarded region.
__device__ __forceinline__ float quad_xor1(float x) {
    return __int_as_float(
        __builtin_amdgcn_update_dpp(0, __float_as_int(x), 0xB1, 0xF, 0xF, true));
}
__device__ __forceinline__ float quad_xor2(float x) {
    return __int_as_float(
        __builtin_amdgcn_update_dpp(0, __float_as_int(x), 0x4E, 0xF, 0xF, true));
}

// Block = (bh, parity, strip). Outputs rows y0+2j, j=0..3. LDS = 3-slot ring
// of k/v row-planes in [d][x'] layout (XPAD 61, zero-pad baked in). Rolling
// schedule: prefetch row r=j+3 (and next q) into regs DURING compute of row j,
// commit to slot j%3 after the barrier. 672 blocks x 46.8KB = whole grid
// co-resident at 3 blocks/CU; every compute phase has loads in flight.
__global__ __launch_bounds__(256, 4) void dilate_attn_roll(
    const float* __restrict__ q,
    const float* __restrict__ k,
    const float* __restrict__ v,
    float* __restrict__ out)
{
    __shared__ float ks[3][ROWSZ];
    __shared__ float vs[3][ROWSZ];

    // bh fastest -> (bh, strip±1) partners 48 apart (same XCD, co-resident)
    const int bh     = blockIdx.x % 48;
    const int ps     = blockIdx.x / 48;
    const int parity = ps / STRIPS;
    const int s      = ps % STRIPS;
    const int y0     = parity + 8 * s;    // output rows y0 + 2j
    const int t      = threadIdx.x;

    const size_t plane = (size_t)bh * HEAD_DIM * HWSZ;
    const int px = t >> 2;                // 0..63 (valid < 56)
    const int c  = t & 3;                 // dim-octet
    const bool active = px < WW;

    // staging element map: 7 elems/thread per row (7*256 = 1792 = 32*56)
    int sd[7], sx[7];
#pragma unroll
    for (int i = 0; i < 7; i++) {
        const int e = t + 256 * i;
        sd[i] = e / WW;
        sx[i] = e - sd[i] * WW;
    }

    // ---- q for row 0 (issue first; overlaps prologue staging) ----
    float qcur[8];
    if (active) {
        const float* qb = q + plane + (size_t)(8 * c) * HWSZ + (size_t)y0 * WW + px;
#pragma unroll
        for (int j = 0; j < 8; j++) qcur[j] = qb[j * HWSZ];
    }

    // ---- zero pad columns x' in {0,1,58,59} for all 3 slots (done ONCE;
    //      row data never overwrites pads) ----
    for (int e = t; e < 3 * HEAD_DIM * 4; e += 256) {
        const int slot = e >> 7;
        const int rr   = e & 127;
        const int d    = rr >> 2;
        const int xc   = rr & 3;
        const int xp   = (xc < 2) ? xc : (56 + xc);
        ks[slot][d * XPAD + xp] = 0.0f;
        vs[slot][d * XPAD + xp] = 0.0f;
    }

    // ---- prologue: stage rows r=0,1,2 (ky = y0-2+2r) into slots 0,1,2 ----
    float kpre[7], vpre[7];
#pragma unroll
    for (int r = 0; r < 3; r++) {
        const int ky   = y0 - 2 + 2 * r;
        const bool okr = (ky >= 0) && (ky < HH);
#pragma unroll
        for (int i = 0; i < 7; i++) {
            const size_t g = plane + (size_t)sd[i] * HWSZ + (size_t)(okr ? ky : 0) * WW + sx[i];
            kpre[i] = okr ? k[g] : 0.0f;
            vpre[i] = okr ? v[g] : 0.0f;
        }
#pragma unroll
        for (int i = 0; i < 7; i++) {
            const int a = sd[i] * XPAD + sx[i] + 2;
            ks[r][a] = kpre[i];
            vs[r][a] = vpre[i];
        }
    }
    __syncthreads();

    // ---- main rolling loop over the 4 output rows ----
    float qnxt[8];
#pragma unroll
    for (int j = 0; j < JROWS; j++) {
        const int y = y0 + 2 * j;

        // prefetch staged row r=j+3 (ky = y0+4+2j) + next q into registers
        if (j < 3) {
            const int ky   = y0 + 4 + 2 * j;       // always >= 4
            const bool okr = (ky < HH);
#pragma unroll
            for (int i = 0; i < 7; i++) {
                const size_t g = plane + (size_t)sd[i] * HWSZ + (size_t)(okr ? ky : 0) * WW + sx[i];
                kpre[i] = okr ? k[g] : 0.0f;
                vpre[i] = okr ? v[g] : 0.0f;
            }
            if (active) {
                const float* qb = q + plane + (size_t)(8 * c) * HWSZ + (size_t)(y + 2) * WW + px;
#pragma unroll
                for (int jj = 0; jj < 8; jj++) qnxt[jj] = qb[jj * HWSZ];
            }
        }

        // compute output row j from slots (j+r')%3, r'=0..2 (loads in flight)
        if (active) {
            float lg[KPOS];
#pragma unroll
            for (int rp = 0; rp < 3; rp++) {
                const float* kr = &ks[(j + rp) % 3][(8 * c) * XPAD + px];
                float a0 = 0.f, a1 = 0.f, a2 = 0.f;
#pragma unroll
                for (int j8 = 0; j8 < 8; j8++) {
                    const float* p  = kr + j8 * XPAD;
                    const float qj = qcur[j8];
                    a0 = fmaf(qj, p[0], a0);
                    a1 = fmaf(qj, p[2], a1);
                    a2 = fmaf(qj, p[4], a2);
                }
                lg[3 * rp + 0] = a0;
                lg[3 * rp + 1] = a1;
                lg[3 * rp + 2] = a2;
            }
            // quad reduction via DPP (VALU) — no LDS-pipe traffic
#pragma unroll
            for (int kk = 0; kk < KPOS; kk++) {
                float sm = lg[kk];
                sm += quad_xor1(sm);
                sm += quad_xor2(sm);
                lg[kk] = sm * SCALE_LOG2E;   // logits in log2 domain
            }
            // tree max (depth 2; clang fuses v_max3)
            const float m = fmaxf(fmaxf(fmaxf(lg[0], lg[1]), lg[2]),
                                  fmaxf(fmaxf(fmaxf(lg[3], lg[4]), lg[5]),
                                        fmaxf(fmaxf(lg[6], lg[7]), lg[8])));
            float ssum = 0.f;
#pragma unroll
            for (int kk = 0; kk < KPOS; kk++) {
                lg[kk] = exp2f(lg[kk] - m);   // single v_exp_f32
                ssum += lg[kk];
            }
            const float inv = __builtin_amdgcn_rcpf(ssum);

            // PV with UNNORMALIZED weights (bounded <=1); normalize at epilogue.
            // rcp latency hides under the PV FMAs.
            float acc[8];
#pragma unroll
            for (int jj = 0; jj < 8; jj++) acc[jj] = 0.f;
#pragma unroll
            for (int rp = 0; rp < 3; rp++) {
                const float* vr = &vs[(j + rp) % 3][(8 * c) * XPAD + px];
                const float w0 = lg[3 * rp + 0];
                const float w1 = lg[3 * rp + 1];
                const float w2 = lg[3 * rp + 2];
#pragma unroll
                for (int jj = 0; jj < 8; jj++) {
                    const float* p = vr + jj * XPAD;
                    float a = acc[jj];
                    a = fmaf(w0, p[0], a);
                    a = fmaf(w1, p[2], a);
                    a = fmaf(w2, p[4], a);
                    acc[jj] = a;
                }
            }

            const int h = bh % NH;
            const int b = bh / NH;
            float* ob = out + ((size_t)((b * HH + y) * WW + px)) * CCH
                            + h * HEAD_DIM + 8 * c;
            reinterpret_cast<float4*>(ob)[0] =
                make_float4(acc[0] * inv, acc[1] * inv, acc[2] * inv, acc[3] * inv);
            reinterpret_cast<float4*>(ob)[1] =
                make_float4(acc[4] * inv, acc[5] * inv, acc[6] * inv, acc[7] * inv);
        }

        __syncthreads();    // all waves done reading slot j%3

        if (j < 3) {
            // commit prefetched row r=j+3 into slot j%3; roll q
#pragma unroll
            for (int i = 0; i < 7; i++) {
                const int a = sd[i] * XPAD + sx[i] + 2;
                ks[j % 3][a] = kpre[i];
                vs[j % 3][a] = vpre[i];
            }
#pragma unroll
            for (int jj = 0; jj < 8; jj++) qcur[jj] = qnxt[jj];
        }

        __syncthreads();    // new slot contents visible before next compute
    }
}

extern "C" void kernel_launch(void* const* d_in, const int* in_sizes, int n_in,
                              void* d_out, int out_size, void* d_ws, size_t ws_size,
                              hipStream_t stream) {
    const float* q = (const float*)d_in[0];
    const float* k = (const float*)d_in[1];
    const float* v = (const float*)d_in[2];
    float* out = (float*)d_out;

    const int blocks = 48 * 2 * STRIPS;   // 672 — fully co-resident at 3/CU
    dilate_attn_roll<<<blocks, 256, 0, stream>>>(q, k, v, out);
}